// Round 10
// baseline (83.805 us; speedup 1.0000x reference)
//
#include <hip/hip_runtime.h>
#include <math.h>

#define NFEAT 32
#define EMB   30
#define ATT   10
#define NPAIR 496   // 32*31/2
#define BLK   128
#define WPB   2     // waves per block = batch elements per block
#define ROWSTR 36   // padded x-row stride in floats (144B; 4-bank shift per row)

typedef float v2f __attribute__((ext_vector_type(2)));

// Forced VOP3P: acc += broadcast(pr.lo or pr.hi) * w   (w in SGPR pair)
#define PK_FMA_BCLO(acc, pr, w) \
    asm("v_pk_fma_f32 %0, %1, %2, %0 op_sel:[0,0,0] op_sel_hi:[0,1,1]" \
        : "+v"(acc) : "v"(pr), "s"(w))
#define PK_FMA_BCHI(acc, pr, w) \
    asm("v_pk_fma_f32 %0, %1, %2, %0 op_sel:[1,0,0] op_sel_hi:[1,1,1]" \
        : "+v"(acc) : "v"(pr), "s"(w))
#define PK_MUL(d, a, b) \
    asm("v_pk_mul_f32 %0, %1, %2" : "=v"(d) : "v"(a), "v"(b))

// R9 lesson: occupancy model -- effective VGPR pool ~= 256/wave-slot here
// (R0 204reg->1w/SIMD, R1 lb(256,4)->64 cap, R4-R9 ~52reg->~4w/SIMD, occ 31-39%).
// Latency-bound: LDS pipe ~10us/CU and VALU ~12us/SIMD both at ~32% duty.
// R10 = R7 structure (best, 37.7us) + accC v2f->scalar (-4 VGPR) + wpe(5)
// (forces alloc <=48 -> 5 waves/SIMD, +25% residency).
__global__ __launch_bounds__(BLK) __attribute__((amdgpu_waves_per_eu(5)))
void attn_net_kernel(const float* __restrict__ x,
                     const float* __restrict__ W,
                     const float* __restrict__ bias,
                     const float* __restrict__ h,
                     const float* __restrict__ pvec,
                     float* __restrict__ out)
{
    __shared__ __align__(16) float sx[WPB * NFEAT * ROWSTR];  // 9 KiB

    const int t    = threadIdx.x;
    const int wid  = t >> 6;
    const int lane = t & 63;
    const int b    = blockIdx.x * WPB + wid;

    // ---- stage x[b] into this wave's padded LDS rows (wave-private: no barrier).
    //      cols 30..35 uninitialized: eg=7 consumes only e=28,29. ----
    float* swx = sx + wid * (NFEAT * ROWSTR);
    {
        const float4* xin = reinterpret_cast<const float4*>(x + (size_t)b * (NFEAT * EMB));
        for (int v = lane; v < 240; v += 64) {          // exactly 240 float4s
            const float4 d = xin[v];
            const int ef = 4 * v;
            #pragma unroll
            for (int u = 0; u < 4; ++u) {
                const int e = ef + u;
                const int r = e / EMB;
                const int c = e - r * EMB;
                swx[r * ROWSTR + c] = ((const float*)&d)[u];
            }
        }
    }

    // ---- uniform params (scalar s_loads -> SGPRs) ----
    v2f b2[5], h2[5];
    #pragma unroll
    for (int a2 = 0; a2 < 5; ++a2) {
        b2[a2] = v2f{bias[2 * a2], bias[2 * a2 + 1]};
        h2[a2] = v2f{h[2 * a2],    h[2 * a2 + 1]};
    }

    // ---- per-lane: 2 chunks x one 2x2 tile (4 pairs); online softmax ----
    float m = -INFINITY, se = 0.f, sec = 0.f;

    #pragma unroll
    for (int ch = 0; ch < 2; ++ch) {
        const int T = ch * 64 + lane;
        const bool special = (T >= 120);                // only ch==1, lanes 56..63
        int r0, r1, c0, c1;
        if (special) {
            const int s7 = T - 120;
            r0 = 4 * s7; r1 = r0 + 2; c0 = r0 + 1; c1 = r0 + 3;
        } else {
            // n=16 triu inversion; exact: 961-8*T_I=(31-2I)^2, margin>=4/29
            const float sq = sqrtf((float)(961 - 8 * T));
            const int I = (int)((31.0f - sq) * 0.5f);
            const int J = I + 1 + (T - ((I * (31 - I)) >> 1));
            r0 = 2 * I; r1 = r0 + 1; c0 = 2 * J; c1 = c0 + 1;
        }
        const int oi0 = r0 * ROWSTR, oi1 = r1 * ROWSTR;
        const int oj0 = c0 * ROWSTR, oj1 = c1 * ROWSTR;

        // slots: 0:(r0,c0) 1:(r0,c1) 2:(r1,c0) 3:(r1,c1); special masks 1,2
        v2f   acc[4][5];                                // 40 VGPR
        float accC[4];                                  // 4 VGPR (scalar, was v2f)
        #pragma unroll
        for (int p = 0; p < 4; ++p) {
            #pragma unroll
            for (int a2 = 0; a2 < 5; ++a2) acc[p][a2] = b2[a2];
            accC[p] = 0.f;
        }

        #pragma unroll
        for (int eg = 0; eg < 8; ++eg) {                // e-groups of 4; eg=7 -> e=28,29
            const int e0 = eg * 4;
            const bool full = (eg < 7);
            // W rows for this e-group -> SGPR pairs (shared by all 4 pairs)
            v2f wa[5], wb[5], wc[5], wd[5];
            #pragma unroll
            for (int a2 = 0; a2 < 5; ++a2) {
                wa[a2] = v2f{W[(e0    ) * ATT + 2*a2], W[(e0    ) * ATT + 2*a2 + 1]};
                wb[a2] = v2f{W[(e0 + 1) * ATT + 2*a2], W[(e0 + 1) * ATT + 2*a2 + 1]};
            }
            if (full) {
                #pragma unroll
                for (int a2 = 0; a2 < 5; ++a2) {
                    wc[a2] = v2f{W[(e0 + 2) * ATT + 2*a2], W[(e0 + 2) * ATT + 2*a2 + 1]};
                    wd[a2] = v2f{W[(e0 + 3) * ATT + 2*a2], W[(e0 + 3) * ATT + 2*a2 + 1]};
                }
            }
            const float pv0 = pvec[e0],     pv1 = pvec[e0 + 1];
            float pv2 = 0.f, pv3 = 0.f;
            if (full) { pv2 = pvec[e0 + 2]; pv3 = pvec[e0 + 3]; }

            const float4 xi0 = *reinterpret_cast<const float4*>(&swx[oi0 + e0]);
            const float4 xi1 = *reinterpret_cast<const float4*>(&swx[oi1 + e0]);

            auto do_pair = [&](v2f* ap, float& cp, const float4& xi, const float4& xj) {
                const v2f* xiv = reinterpret_cast<const v2f*>(&xi);
                const v2f* xjv = reinterpret_cast<const v2f*>(&xj);
                v2f prL;
                PK_MUL(prL, xiv[0], xjv[0]);
                #pragma unroll
                for (int a2 = 0; a2 < 5; ++a2) PK_FMA_BCLO(ap[a2], prL, wa[a2]);
                #pragma unroll
                for (int a2 = 0; a2 < 5; ++a2) PK_FMA_BCHI(ap[a2], prL, wb[a2]);
                cp = fmaf(prL.x, pv0, cp);
                cp = fmaf(prL.y, pv1, cp);
                if (full) {
                    v2f prH;
                    PK_MUL(prH, xiv[1], xjv[1]);
                    #pragma unroll
                    for (int a2 = 0; a2 < 5; ++a2) PK_FMA_BCLO(ap[a2], prH, wc[a2]);
                    #pragma unroll
                    for (int a2 = 0; a2 < 5; ++a2) PK_FMA_BCHI(ap[a2], prH, wd[a2]);
                    cp = fmaf(prH.x, pv2, cp);
                    cp = fmaf(prH.y, pv3, cp);
                }
            };

            {   // column j0: pairs (r0,c0)->slot0, (r1,c0)->slot2
                const float4 xj = *reinterpret_cast<const float4*>(&swx[oj0 + e0]);
                do_pair(acc[0], accC[0], xi0, xj);
                do_pair(acc[2], accC[2], xi1, xj);
            }
            {   // column j1: pairs (r0,c1)->slot1, (r1,c1)->slot3
                const float4 xj = *reinterpret_cast<const float4*>(&swx[oj1 + e0]);
                do_pair(acc[1], accC[1], xi0, xj);
                do_pair(acc[3], accC[3], xi1, xj);
            }
        }

        float s4[4], cv4[4];
        #pragma unroll
        for (int p = 0; p < 4; ++p) {
            const v2f z = v2f{0.f, 0.f};
            v2f sv = z;
            #pragma unroll
            for (int a2 = 0; a2 < 5; ++a2) {
                const v2f r = __builtin_elementwise_max(acc[p][a2], z);
                sv = __builtin_elementwise_fma(r, h2[a2], sv);
            }
            s4[p]  = sv.x + sv.y;
            cv4[p] = accC[p];
        }
        if (special) { s4[1] = -INFINITY; s4[2] = -INFINITY; }  // dup / i>j slots

        // online merge (ch=0: m=-inf -> scale=0, clean start)
        const float nm = fmaxf(m, fmaxf(fmaxf(s4[0], s4[1]), fmaxf(s4[2], s4[3])));
        const float scale = __expf(m - nm);
        se  *= scale;
        sec *= scale;
        #pragma unroll
        for (int p = 0; p < 4; ++p) {
            const float E = __expf(s4[p] - nm);         // exp(-inf)=0 for masked
            se += E;
            sec = fmaf(E, cv4[p], sec);
        }
        m = nm;
    }

    // ---- tail: global max first, one rescale, then add-butterflies ----
    float M = m;
    #pragma unroll
    for (int o = 1; o < 64; o <<= 1) M = fmaxf(M, __shfl_xor(M, o, 64));
    const float rs = __expf(m - M);
    se  *= rs;
    sec *= rs;
    #pragma unroll
    for (int o = 1; o < 64; o <<= 1) {
        se  += __shfl_xor(se,  o, 64);
        sec += __shfl_xor(sec, o, 64);
    }
    if (lane == 0) out[b] = sec / se;
}

extern "C" void kernel_launch(void* const* d_in, const int* in_sizes, int n_in,
                              void* d_out, int out_size, void* d_ws, size_t ws_size,
                              hipStream_t stream) {
    const float* x    = (const float*)d_in[0];
    const float* W    = (const float*)d_in[1];
    const float* bias = (const float*)d_in[2];
    const float* h    = (const float*)d_in[3];
    const float* pvec = (const float*)d_in[4];
    float* out = (float*)d_out;

    const int B = in_sizes[0] / (NFEAT * EMB);   // 8192
    attn_net_kernel<<<B / WPB, BLK, 0, stream>>>(x, W, bias, h, pvec, out);
}

// Round 11
// 45.479 us; speedup vs baseline: 1.8427x; 1.8427x over previous
//
#include <hip/hip_runtime.h>
#include <math.h>

#define NFEAT 32
#define EMB   30
#define ATT   10
#define NPAIR 496   // 32*31/2
#define BLK   128
#define WPB   2     // waves per block = batch elements per block
#define ROWSTR 36   // padded x-row stride in floats (144B; 4-bank shift per row)

typedef float v2f __attribute__((ext_vector_type(2)));

// Forced VOP3P: acc += broadcast(pr.lo or pr.hi) * w   (w in SGPR pair)
#define PK_FMA_BCLO(acc, pr, w) \
    asm("v_pk_fma_f32 %0, %1, %2, %0 op_sel:[0,0,0] op_sel_hi:[0,1,1]" \
        : "+v"(acc) : "v"(pr), "s"(w))
#define PK_FMA_BCHI(acc, pr, w) \
    asm("v_pk_fma_f32 %0, %1, %2, %0 op_sel:[1,0,0] op_sel_hi:[1,1,1]" \
        : "+v"(acc) : "v"(pr), "s"(w))
#define PK_MUL(d, a, b) \
    asm("v_pk_mul_f32 %0, %1, %2" : "=v"(d) : "v"(a), "v"(b))

// R10 lesson: natural (un-spilled) pressure is 49-56 -> 52/56 granule -> hard
// 4 waves/SIMD ceiling (pool ~256/wave-slot). Forcing 48 via wpe(5) spilled
// (213MB scratch). R11 = R7 structure @ wpe(3) + accC scalar (-4 regs,
// -120 instr) + b64 staging writes (15->7.5 LDS writes/lane) + reads hoisted
// to one wait-point per eg. Recover 37.7 and trim; probe if alloc lands 48.
__global__ __launch_bounds__(BLK) __attribute__((amdgpu_waves_per_eu(3)))
void attn_net_kernel(const float* __restrict__ x,
                     const float* __restrict__ W,
                     const float* __restrict__ bias,
                     const float* __restrict__ h,
                     const float* __restrict__ pvec,
                     float* __restrict__ out)
{
    __shared__ __align__(16) float sx[WPB * NFEAT * ROWSTR];  // 9 KiB

    const int t    = threadIdx.x;
    const int wid  = t >> 6;
    const int lane = t & 63;
    const int b    = blockIdx.x * WPB + wid;

    // ---- stage x[b] into this wave's padded LDS rows (wave-private: no barrier).
    //      b64 writes: row len 30 is even -> each float4 = two intra-row pairs;
    //      (r*36+c)*4 is 8B-aligned for even c. cols 30..35 uninitialized
    //      (eg=7 consumes only e=28,29). ----
    float* swx = sx + wid * (NFEAT * ROWSTR);
    {
        const float4* xin = reinterpret_cast<const float4*>(x + (size_t)b * (NFEAT * EMB));
        for (int v = lane; v < 240; v += 64) {          // exactly 240 float4s
            const float4 d = xin[v];
            const int e0 = 4 * v;
            const int r0 = e0 / EMB, c0 = e0 - r0 * EMB;
            const int e2 = e0 + 2;
            const int r2 = e2 / EMB, c2 = e2 - r2 * EMB;
            *reinterpret_cast<v2f*>(&swx[r0 * ROWSTR + c0]) = v2f{d.x, d.y};
            *reinterpret_cast<v2f*>(&swx[r2 * ROWSTR + c2]) = v2f{d.z, d.w};
        }
    }

    // ---- uniform params (scalar s_loads -> SGPRs) ----
    v2f b2[5], h2[5];
    #pragma unroll
    for (int a2 = 0; a2 < 5; ++a2) {
        b2[a2] = v2f{bias[2 * a2], bias[2 * a2 + 1]};
        h2[a2] = v2f{h[2 * a2],    h[2 * a2 + 1]};
    }

    // ---- per-lane: 2 chunks x one 2x2 tile (4 pairs); online softmax ----
    float m = -INFINITY, se = 0.f, sec = 0.f;

    #pragma unroll
    for (int ch = 0; ch < 2; ++ch) {
        const int T = ch * 64 + lane;
        const bool special = (T >= 120);                // only ch==1, lanes 56..63
        int r0, r1, c0, c1;
        if (special) {
            const int s7 = T - 120;
            r0 = 4 * s7; r1 = r0 + 2; c0 = r0 + 1; c1 = r0 + 3;
        } else {
            // n=16 triu inversion; exact: 961-8*T_I=(31-2I)^2, margin>=4/29
            const float sq = sqrtf((float)(961 - 8 * T));
            const int I = (int)((31.0f - sq) * 0.5f);
            const int J = I + 1 + (T - ((I * (31 - I)) >> 1));
            r0 = 2 * I; r1 = r0 + 1; c0 = 2 * J; c1 = c0 + 1;
        }
        const int oi0 = r0 * ROWSTR, oi1 = r1 * ROWSTR;
        const int oj0 = c0 * ROWSTR, oj1 = c1 * ROWSTR;

        // slots: 0:(r0,c0) 1:(r0,c1) 2:(r1,c0) 3:(r1,c1); special masks 1,2
        v2f   acc[4][5];                                // 40 VGPR
        float accC[4];                                  // 4 VGPR (scalar)
        #pragma unroll
        for (int p = 0; p < 4; ++p) {
            #pragma unroll
            for (int a2 = 0; a2 < 5; ++a2) acc[p][a2] = b2[a2];
            accC[p] = 0.f;
        }

        #pragma unroll
        for (int eg = 0; eg < 8; ++eg) {                // e-groups of 4; eg=7 -> e=28,29
            const int e0 = eg * 4;
            const bool full = (eg < 7);

            // all 4 LDS reads up front: one lgkmcnt wait point per eg
            const float4 xi0 = *reinterpret_cast<const float4*>(&swx[oi0 + e0]);
            const float4 xi1 = *reinterpret_cast<const float4*>(&swx[oi1 + e0]);
            const float4 xj0 = *reinterpret_cast<const float4*>(&swx[oj0 + e0]);
            const float4 xj1 = *reinterpret_cast<const float4*>(&swx[oj1 + e0]);

            // W rows for this e-group -> SGPR pairs (shared by all 4 pairs)
            v2f wa[5], wb[5], wc[5], wd[5];
            #pragma unroll
            for (int a2 = 0; a2 < 5; ++a2) {
                wa[a2] = v2f{W[(e0    ) * ATT + 2*a2], W[(e0    ) * ATT + 2*a2 + 1]};
                wb[a2] = v2f{W[(e0 + 1) * ATT + 2*a2], W[(e0 + 1) * ATT + 2*a2 + 1]};
            }
            if (full) {
                #pragma unroll
                for (int a2 = 0; a2 < 5; ++a2) {
                    wc[a2] = v2f{W[(e0 + 2) * ATT + 2*a2], W[(e0 + 2) * ATT + 2*a2 + 1]};
                    wd[a2] = v2f{W[(e0 + 3) * ATT + 2*a2], W[(e0 + 3) * ATT + 2*a2 + 1]};
                }
            }
            const float pv0 = pvec[e0],     pv1 = pvec[e0 + 1];
            float pv2 = 0.f, pv3 = 0.f;
            if (full) { pv2 = pvec[e0 + 2]; pv3 = pvec[e0 + 3]; }

            auto do_pair = [&](v2f* ap, float& cp, const float4& xi, const float4& xj) {
                const v2f* xiv = reinterpret_cast<const v2f*>(&xi);
                const v2f* xjv = reinterpret_cast<const v2f*>(&xj);
                v2f prL;
                PK_MUL(prL, xiv[0], xjv[0]);
                #pragma unroll
                for (int a2 = 0; a2 < 5; ++a2) PK_FMA_BCLO(ap[a2], prL, wa[a2]);
                #pragma unroll
                for (int a2 = 0; a2 < 5; ++a2) PK_FMA_BCHI(ap[a2], prL, wb[a2]);
                cp = fmaf(prL.x, pv0, cp);
                cp = fmaf(prL.y, pv1, cp);
                if (full) {
                    v2f prH;
                    PK_MUL(prH, xiv[1], xjv[1]);
                    #pragma unroll
                    for (int a2 = 0; a2 < 5; ++a2) PK_FMA_BCLO(ap[a2], prH, wc[a2]);
                    #pragma unroll
                    for (int a2 = 0; a2 < 5; ++a2) PK_FMA_BCHI(ap[a2], prH, wd[a2]);
                    cp = fmaf(prH.x, pv2, cp);
                    cp = fmaf(prH.y, pv3, cp);
                }
            };

            do_pair(acc[0], accC[0], xi0, xj0);
            do_pair(acc[2], accC[2], xi1, xj0);
            do_pair(acc[1], accC[1], xi0, xj1);
            do_pair(acc[3], accC[3], xi1, xj1);
        }

        float s4[4], cv4[4];
        #pragma unroll
        for (int p = 0; p < 4; ++p) {
            const v2f z = v2f{0.f, 0.f};
            v2f sv = z;
            #pragma unroll
            for (int a2 = 0; a2 < 5; ++a2) {
                const v2f r = __builtin_elementwise_max(acc[p][a2], z);
                sv = __builtin_elementwise_fma(r, h2[a2], sv);
            }
            s4[p]  = sv.x + sv.y;
            cv4[p] = accC[p];
        }
        if (special) { s4[1] = -INFINITY; s4[2] = -INFINITY; }  // dup / i>j slots

        // online merge (ch=0: m=-inf -> scale=0, clean start)
        const float nm = fmaxf(m, fmaxf(fmaxf(s4[0], s4[1]), fmaxf(s4[2], s4[3])));
        const float scale = __expf(m - nm);
        se  *= scale;
        sec *= scale;
        #pragma unroll
        for (int p = 0; p < 4; ++p) {
            const float E = __expf(s4[p] - nm);         // exp(-inf)=0 for masked
            se += E;
            sec = fmaf(E, cv4[p], sec);
        }
        m = nm;
    }

    // ---- tail: global max first, one rescale, then add-butterflies ----
    float M = m;
    #pragma unroll
    for (int o = 1; o < 64; o <<= 1) M = fmaxf(M, __shfl_xor(M, o, 64));
    const float rs = __expf(m - M);
    se  *= rs;
    sec *= rs;
    #pragma unroll
    for (int o = 1; o < 64; o <<= 1) {
        se  += __shfl_xor(se,  o, 64);
        sec += __shfl_xor(sec, o, 64);
    }
    if (lane == 0) out[b] = sec / se;
}

extern "C" void kernel_launch(void* const* d_in, const int* in_sizes, int n_in,
                              void* d_out, int out_size, void* d_ws, size_t ws_size,
                              hipStream_t stream) {
    const float* x    = (const float*)d_in[0];
    const float* W    = (const float*)d_in[1];
    const float* bias = (const float*)d_in[2];
    const float* h    = (const float*)d_in[3];
    const float* pvec = (const float*)d_in[4];
    float* out = (float*)d_out;

    const int B = in_sizes[0] / (NFEAT * EMB);   // 8192
    attn_net_kernel<<<B / WPB, BLK, 0, stream>>>(x, W, bias, h, pvec, out);
}

// Round 12
// 40.538 us; speedup vs baseline: 2.0673x; 1.1219x over previous
//
#include <hip/hip_runtime.h>
#include <math.h>

#define NFEAT 32
#define EMB   30
#define ATT   10
#define NPAIR 496   // 32*31/2
#define BLK   128
#define WPB   2     // waves per block = batch elements per block
#define ROWSTR 36   // padded x-row stride in floats (144B; 4-bank shift per row)

typedef float v2f __attribute__((ext_vector_type(2)));

// Forced VOP3P: acc += broadcast(pr.lo or pr.hi) * w   (w in SGPR pair)
#define PK_FMA_BCLO(acc, pr, w) \
    asm("v_pk_fma_f32 %0, %1, %2, %0 op_sel:[0,0,0] op_sel_hi:[0,1,1]" \
        : "+v"(acc) : "v"(pr), "s"(w))
#define PK_FMA_BCHI(acc, pr, w) \
    asm("v_pk_fma_f32 %0, %1, %2, %0 op_sel:[1,0,0] op_sel_hi:[1,1,1]" \
        : "+v"(acc) : "v"(pr), "s"(w))
#define PK_FMA(acc, a, b) \
    asm("v_pk_fma_f32 %0, %1, %2, %0" : "+v"(acc) : "v"(a), "s"(b))
#define PK_MUL(d, a, b) \
    asm("v_pk_mul_f32 %0, %1, %2" : "=v"(d) : "v"(a), "v"(b))

// R8-R11 all failed to beat R7 (37.7us): pipeline/hoist raise VGPR (R8 64,
// R11 84), finer blocks add sync cost (R9 41), forced occupancy spills
// (R10 213MB scratch). Natural pressure ~52-56 -> hard 4 waves/SIMD.
// R12 = R7 VERBATIM + s_setprio(1/0) around each eg's FMA region (T5:
// pays on barrier-free out-of-phase waves; zero reg/code cost).
__global__ __launch_bounds__(BLK) __attribute__((amdgpu_waves_per_eu(3)))
void attn_net_kernel(const float* __restrict__ x,
                     const float* __restrict__ W,
                     const float* __restrict__ bias,
                     const float* __restrict__ h,
                     const float* __restrict__ pvec,
                     float* __restrict__ out)
{
    __shared__ __align__(16) float sx[WPB * NFEAT * ROWSTR];  // 9 KiB

    const int t    = threadIdx.x;
    const int wid  = t >> 6;
    const int lane = t & 63;
    const int b    = blockIdx.x * WPB + wid;

    // ---- stage x[b] into this wave's padded LDS rows (wave-private: no barrier).
    //      cols 30..35 uninitialized: eg=7 consumes only e=28,29. ----
    float* swx = sx + wid * (NFEAT * ROWSTR);
    {
        const float4* xin = reinterpret_cast<const float4*>(x + (size_t)b * (NFEAT * EMB));
        for (int v = lane; v < 240; v += 64) {          // exactly 240 float4s
            const float4 d = xin[v];
            const int ef = 4 * v;
            #pragma unroll
            for (int u = 0; u < 4; ++u) {
                const int e = ef + u;
                const int r = e / EMB;
                const int c = e - r * EMB;
                swx[r * ROWSTR + c] = ((const float*)&d)[u];
            }
        }
    }

    // ---- uniform params (scalar s_loads -> SGPRs) ----
    v2f b2[5], h2[5];
    #pragma unroll
    for (int a2 = 0; a2 < 5; ++a2) {
        b2[a2] = v2f{bias[2 * a2], bias[2 * a2 + 1]};
        h2[a2] = v2f{h[2 * a2],    h[2 * a2 + 1]};
    }

    // ---- per-lane: 2 chunks x one 2x2 tile (4 pairs); online softmax ----
    float m = -INFINITY, se = 0.f, sec = 0.f;

    #pragma unroll
    for (int ch = 0; ch < 2; ++ch) {
        const int T = ch * 64 + lane;
        const bool special = (T >= 120);                // only ch==1, lanes 56..63
        int r0, r1, c0, c1;
        if (special) {
            const int s7 = T - 120;
            r0 = 4 * s7; r1 = r0 + 2; c0 = r0 + 1; c1 = r0 + 3;
        } else {
            // n=16 triu inversion; exact: 961-8*T_I=(31-2I)^2, margin>=4/29
            const float sq = sqrtf((float)(961 - 8 * T));
            const int I = (int)((31.0f - sq) * 0.5f);
            const int J = I + 1 + (T - ((I * (31 - I)) >> 1));
            r0 = 2 * I; r1 = r0 + 1; c0 = 2 * J; c1 = c0 + 1;
        }
        const int oi0 = r0 * ROWSTR, oi1 = r1 * ROWSTR;
        const int oj0 = c0 * ROWSTR, oj1 = c1 * ROWSTR;

        // slots: 0:(r0,c0) 1:(r0,c1) 2:(r1,c0) 3:(r1,c1); special masks 1,2
        v2f acc[4][5];                                  // 40 VGPR
        v2f accC[4];                                    // 8 VGPR (e-pair packed)
        #pragma unroll
        for (int p = 0; p < 4; ++p) {
            #pragma unroll
            for (int a2 = 0; a2 < 5; ++a2) acc[p][a2] = b2[a2];
            accC[p] = v2f{0.f, 0.f};
        }

        #pragma unroll
        for (int eg = 0; eg < 8; ++eg) {                // e-groups of 4; eg=7 -> e=28,29
            const int e0 = eg * 4;
            const bool full = (eg < 7);
            // W rows for this e-group -> SGPR pairs (shared by all 4 pairs)
            v2f wa[5], wb[5], wc[5], wd[5];
            #pragma unroll
            for (int a2 = 0; a2 < 5; ++a2) {
                wa[a2] = v2f{W[(e0    ) * ATT + 2*a2], W[(e0    ) * ATT + 2*a2 + 1]};
                wb[a2] = v2f{W[(e0 + 1) * ATT + 2*a2], W[(e0 + 1) * ATT + 2*a2 + 1]};
            }
            if (full) {
                #pragma unroll
                for (int a2 = 0; a2 < 5; ++a2) {
                    wc[a2] = v2f{W[(e0 + 2) * ATT + 2*a2], W[(e0 + 2) * ATT + 2*a2 + 1]};
                    wd[a2] = v2f{W[(e0 + 3) * ATT + 2*a2], W[(e0 + 3) * ATT + 2*a2 + 1]};
                }
            }
            const v2f pv01 = v2f{pvec[e0], pvec[e0 + 1]};
            v2f pv23 = v2f{0.f, 0.f};
            if (full) pv23 = v2f{pvec[e0 + 2], pvec[e0 + 3]};

            const float4 xi0 = *reinterpret_cast<const float4*>(&swx[oi0 + e0]);
            const float4 xi1 = *reinterpret_cast<const float4*>(&swx[oi1 + e0]);

            auto do_pair = [&](v2f* ap, v2f& cp, const float4& xi, const float4& xj) {
                const v2f* xiv = reinterpret_cast<const v2f*>(&xi);
                const v2f* xjv = reinterpret_cast<const v2f*>(&xj);
                v2f prL;
                PK_MUL(prL, xiv[0], xjv[0]);
                #pragma unroll
                for (int a2 = 0; a2 < 5; ++a2) PK_FMA_BCLO(ap[a2], prL, wa[a2]);
                #pragma unroll
                for (int a2 = 0; a2 < 5; ++a2) PK_FMA_BCHI(ap[a2], prL, wb[a2]);
                PK_FMA(cp, prL, pv01);
                if (full) {
                    v2f prH;
                    PK_MUL(prH, xiv[1], xjv[1]);
                    #pragma unroll
                    for (int a2 = 0; a2 < 5; ++a2) PK_FMA_BCLO(ap[a2], prH, wc[a2]);
                    #pragma unroll
                    for (int a2 = 0; a2 < 5; ++a2) PK_FMA_BCHI(ap[a2], prH, wd[a2]);
                    PK_FMA(cp, prH, pv23);
                }
            };

            __builtin_amdgcn_s_setprio(1);              // favor FMA-ready waves (T5)
            {   // column j0: pairs (r0,c0)->slot0, (r1,c0)->slot2
                const float4 xj = *reinterpret_cast<const float4*>(&swx[oj0 + e0]);
                do_pair(acc[0], accC[0], xi0, xj);
                do_pair(acc[2], accC[2], xi1, xj);
            }
            {   // column j1: pairs (r0,c1)->slot1, (r1,c1)->slot3
                const float4 xj = *reinterpret_cast<const float4*>(&swx[oj1 + e0]);
                do_pair(acc[1], accC[1], xi0, xj);
                do_pair(acc[3], accC[3], xi1, xj);
            }
            __builtin_amdgcn_s_setprio(0);
        }

        float s4[4], cv4[4];
        #pragma unroll
        for (int p = 0; p < 4; ++p) {
            const v2f z = v2f{0.f, 0.f};
            v2f sv = z;
            #pragma unroll
            for (int a2 = 0; a2 < 5; ++a2) {
                const v2f r = __builtin_elementwise_max(acc[p][a2], z);
                sv = __builtin_elementwise_fma(r, h2[a2], sv);
            }
            s4[p]  = sv.x + sv.y;
            cv4[p] = accC[p].x + accC[p].y;
        }
        if (special) { s4[1] = -INFINITY; s4[2] = -INFINITY; }  // dup / i>j slots

        // online merge (ch=0: m=-inf -> scale=0, clean start)
        const float nm = fmaxf(m, fmaxf(fmaxf(s4[0], s4[1]), fmaxf(s4[2], s4[3])));
        const float scale = __expf(m - nm);
        se  *= scale;
        sec *= scale;
        #pragma unroll
        for (int p = 0; p < 4; ++p) {
            const float E = __expf(s4[p] - nm);         // exp(-inf)=0 for masked
            se += E;
            sec = fmaf(E, cv4[p], sec);
        }
        m = nm;
    }

    // ---- tail: global max first, one rescale, then add-butterflies ----
    float M = m;
    #pragma unroll
    for (int o = 1; o < 64; o <<= 1) M = fmaxf(M, __shfl_xor(M, o, 64));
    const float rs = __expf(m - M);
    se  *= rs;
    sec *= rs;
    #pragma unroll
    for (int o = 1; o < 64; o <<= 1) {
        se  += __shfl_xor(se,  o, 64);
        sec += __shfl_xor(sec, o, 64);
    }
    if (lane == 0) out[b] = sec / se;
}

extern "C" void kernel_launch(void* const* d_in, const int* in_sizes, int n_in,
                              void* d_out, int out_size, void* d_ws, size_t ws_size,
                              hipStream_t stream) {
    const float* x    = (const float*)d_in[0];
    const float* W    = (const float*)d_in[1];
    const float* bias = (const float*)d_in[2];
    const float* h    = (const float*)d_in[3];
    const float* pvec = (const float*)d_in[4];
    float* out = (float*)d_out;

    const int B = in_sizes[0] / (NFEAT * EMB);   // 8192
    attn_net_kernel<<<B / WPB, BLK, 0, stream>>>(x, W, bias, h, pvec, out);
}

// Round 13
// 39.015 us; speedup vs baseline: 2.1480x; 1.0390x over previous
//
#include <hip/hip_runtime.h>
#include <math.h>

#define NFEAT 32
#define EMB   30
#define ATT   10
#define NPAIR 496   // 32*31/2
#define BLK   128
#define WPB   2     // waves per block = batch elements per block
#define ROWSTR 36   // padded x-row stride in floats (144B; 4-bank shift per row)

typedef float v2f __attribute__((ext_vector_type(2)));

// Forced VOP3P: acc += broadcast(pr.lo or pr.hi) * w   (w in SGPR pair)
#define PK_FMA_BCLO(acc, pr, w) \
    asm("v_pk_fma_f32 %0, %1, %2, %0 op_sel:[0,0,0] op_sel_hi:[0,1,1]" \
        : "+v"(acc) : "v"(pr), "s"(w))
#define PK_FMA_BCHI(acc, pr, w) \
    asm("v_pk_fma_f32 %0, %1, %2, %0 op_sel:[1,0,0] op_sel_hi:[1,1,1]" \
        : "+v"(acc) : "v"(pr), "s"(w))
#define PK_FMA(acc, a, b) \
    asm("v_pk_fma_f32 %0, %1, %2, %0" : "+v"(acc) : "v"(a), "s"(b))
#define PK_MUL(d, a, b) \
    asm("v_pk_mul_f32 %0, %1, %2" : "=v"(d) : "v"(a), "v"(b))

// R12 datum: 40 VGPR / 40% occupancy was SLOWER than R7's 52/31% -> occupancy
// is not the constraint. Waves wait ~93% of the time with every pipe <30%.
// Remaining suspect: I$ thrash -- R7's fully-unrolled body is ~12-16KB of
// straight-line code vs 32KB shared I$ with 12+ waves at different phases.
// R13 = R7 math/schedule with REAL loops (unroll-disabled): ~3KB code.
__global__ __launch_bounds__(BLK) __attribute__((amdgpu_waves_per_eu(3)))
void attn_net_kernel(const float* __restrict__ x,
                     const float* __restrict__ W,
                     const float* __restrict__ bias,
                     const float* __restrict__ h,
                     const float* __restrict__ pvec,
                     float* __restrict__ out)
{
    __shared__ __align__(16) float sx[WPB * NFEAT * ROWSTR];  // 9 KiB

    const int t    = threadIdx.x;
    const int wid  = t >> 6;
    const int lane = t & 63;
    const int b    = blockIdx.x * WPB + wid;

    // ---- stage x[b] into this wave's padded LDS rows (wave-private: no barrier).
    //      cols 30..35 uninitialized: tail consumes only e=28,29. ----
    float* swx = sx + wid * (NFEAT * ROWSTR);
    {
        const float4* xin = reinterpret_cast<const float4*>(x + (size_t)b * (NFEAT * EMB));
        for (int v = lane; v < 240; v += 64) {          // exactly 240 float4s
            const float4 d = xin[v];
            const int ef = 4 * v;
            #pragma unroll
            for (int u = 0; u < 4; ++u) {
                const int e = ef + u;
                const int r = e / EMB;
                const int c = e - r * EMB;
                swx[r * ROWSTR + c] = ((const float*)&d)[u];
            }
        }
    }

    // ---- uniform params (scalar s_loads -> SGPRs) ----
    v2f b2[5], h2[5];
    #pragma unroll
    for (int a2 = 0; a2 < 5; ++a2) {
        b2[a2] = v2f{bias[2 * a2], bias[2 * a2 + 1]};
        h2[a2] = v2f{h[2 * a2],    h[2 * a2 + 1]};
    }

    // ---- per-lane: 2 chunks x one 2x2 tile (4 pairs); online softmax ----
    float m = -INFINITY, se = 0.f, sec = 0.f;

    #pragma clang loop unroll(disable)
    for (int ch = 0; ch < 2; ++ch) {
        const int T = ch * 64 + lane;
        const bool special = (T >= 120);                // only ch==1, lanes 56..63
        int r0, r1, c0, c1;
        if (special) {
            const int s7 = T - 120;
            r0 = 4 * s7; r1 = r0 + 2; c0 = r0 + 1; c1 = r0 + 3;
        } else {
            // n=16 triu inversion; exact: 961-8*T_I=(31-2I)^2, margin>=4/29
            const float sq = sqrtf((float)(961 - 8 * T));
            const int I = (int)((31.0f - sq) * 0.5f);
            const int J = I + 1 + (T - ((I * (31 - I)) >> 1));
            r0 = 2 * I; r1 = r0 + 1; c0 = 2 * J; c1 = c0 + 1;
        }
        const int oi0 = r0 * ROWSTR, oi1 = r1 * ROWSTR;
        const int oj0 = c0 * ROWSTR, oj1 = c1 * ROWSTR;

        // slots: 0:(r0,c0) 1:(r0,c1) 2:(r1,c0) 3:(r1,c1); special masks 1,2
        v2f acc[4][5];                                  // 40 VGPR
        v2f accC[4];                                    // 8 VGPR (e-pair packed)
        #pragma unroll
        for (int p = 0; p < 4; ++p) {
            #pragma unroll
            for (int a2 = 0; a2 < 5; ++a2) acc[p][a2] = b2[a2];
            accC[p] = v2f{0.f, 0.f};
        }

        // ---- main e-loop: 7 iterations of 4 e's, REAL loop (small code) ----
        #pragma clang loop unroll(disable)
        for (int eg = 0; eg < 7; ++eg) {
            const int e0 = eg * 4;
            v2f wa[5], wb[5], wc[5], wd[5];             // uniform -> SGPRs
            #pragma unroll
            for (int a2 = 0; a2 < 5; ++a2) {
                wa[a2] = v2f{W[(e0    ) * ATT + 2*a2], W[(e0    ) * ATT + 2*a2 + 1]};
                wb[a2] = v2f{W[(e0 + 1) * ATT + 2*a2], W[(e0 + 1) * ATT + 2*a2 + 1]};
                wc[a2] = v2f{W[(e0 + 2) * ATT + 2*a2], W[(e0 + 2) * ATT + 2*a2 + 1]};
                wd[a2] = v2f{W[(e0 + 3) * ATT + 2*a2], W[(e0 + 3) * ATT + 2*a2 + 1]};
            }
            const v2f pv01 = v2f{pvec[e0],     pvec[e0 + 1]};
            const v2f pv23 = v2f{pvec[e0 + 2], pvec[e0 + 3]};

            const float4 xi0 = *reinterpret_cast<const float4*>(&swx[oi0 + e0]);
            const float4 xi1 = *reinterpret_cast<const float4*>(&swx[oi1 + e0]);

            auto pair_full = [&](v2f* ap, v2f& cp, const float4& xi, const float4& xj) {
                const v2f* xiv = reinterpret_cast<const v2f*>(&xi);
                const v2f* xjv = reinterpret_cast<const v2f*>(&xj);
                v2f prL, prH;
                PK_MUL(prL, xiv[0], xjv[0]);
                #pragma unroll
                for (int a2 = 0; a2 < 5; ++a2) PK_FMA_BCLO(ap[a2], prL, wa[a2]);
                #pragma unroll
                for (int a2 = 0; a2 < 5; ++a2) PK_FMA_BCHI(ap[a2], prL, wb[a2]);
                PK_FMA(cp, prL, pv01);
                PK_MUL(prH, xiv[1], xjv[1]);
                #pragma unroll
                for (int a2 = 0; a2 < 5; ++a2) PK_FMA_BCLO(ap[a2], prH, wc[a2]);
                #pragma unroll
                for (int a2 = 0; a2 < 5; ++a2) PK_FMA_BCHI(ap[a2], prH, wd[a2]);
                PK_FMA(cp, prH, pv23);
            };

            {   // column j0: pairs (r0,c0)->slot0, (r1,c0)->slot2
                const float4 xj = *reinterpret_cast<const float4*>(&swx[oj0 + e0]);
                pair_full(acc[0], accC[0], xi0, xj);
                pair_full(acc[2], accC[2], xi1, xj);
            }
            {   // column j1: pairs (r0,c1)->slot1, (r1,c1)->slot3
                const float4 xj = *reinterpret_cast<const float4*>(&swx[oj1 + e0]);
                pair_full(acc[1], accC[1], xi0, xj);
                pair_full(acc[3], accC[3], xi1, xj);
            }
        }

        // ---- tail: e = 28, 29 ----
        {
            const int e0 = 28;
            v2f wa[5], wb[5];
            #pragma unroll
            for (int a2 = 0; a2 < 5; ++a2) {
                wa[a2] = v2f{W[(e0    ) * ATT + 2*a2], W[(e0    ) * ATT + 2*a2 + 1]};
                wb[a2] = v2f{W[(e0 + 1) * ATT + 2*a2], W[(e0 + 1) * ATT + 2*a2 + 1]};
            }
            const v2f pv01 = v2f{pvec[e0], pvec[e0 + 1]};

            const float4 xi0 = *reinterpret_cast<const float4*>(&swx[oi0 + e0]);
            const float4 xi1 = *reinterpret_cast<const float4*>(&swx[oi1 + e0]);

            auto pair_half = [&](v2f* ap, v2f& cp, const float4& xi, const float4& xj) {
                const v2f* xiv = reinterpret_cast<const v2f*>(&xi);
                const v2f* xjv = reinterpret_cast<const v2f*>(&xj);
                v2f prL;
                PK_MUL(prL, xiv[0], xjv[0]);
                #pragma unroll
                for (int a2 = 0; a2 < 5; ++a2) PK_FMA_BCLO(ap[a2], prL, wa[a2]);
                #pragma unroll
                for (int a2 = 0; a2 < 5; ++a2) PK_FMA_BCHI(ap[a2], prL, wb[a2]);
                PK_FMA(cp, prL, pv01);
            };

            {
                const float4 xj = *reinterpret_cast<const float4*>(&swx[oj0 + e0]);
                pair_half(acc[0], accC[0], xi0, xj);
                pair_half(acc[2], accC[2], xi1, xj);
            }
            {
                const float4 xj = *reinterpret_cast<const float4*>(&swx[oj1 + e0]);
                pair_half(acc[1], accC[1], xi0, xj);
                pair_half(acc[3], accC[3], xi1, xj);
            }
        }

        float s4[4], cv4[4];
        #pragma unroll
        for (int p = 0; p < 4; ++p) {
            const v2f z = v2f{0.f, 0.f};
            v2f sv = z;
            #pragma unroll
            for (int a2 = 0; a2 < 5; ++a2) {
                const v2f r = __builtin_elementwise_max(acc[p][a2], z);
                sv = __builtin_elementwise_fma(r, h2[a2], sv);
            }
            s4[p]  = sv.x + sv.y;
            cv4[p] = accC[p].x + accC[p].y;
        }
        if (special) { s4[1] = -INFINITY; s4[2] = -INFINITY; }  // dup / i>j slots

        // online merge (ch=0: m=-inf -> scale=0, clean start)
        const float nm = fmaxf(m, fmaxf(fmaxf(s4[0], s4[1]), fmaxf(s4[2], s4[3])));
        const float scale = __expf(m - nm);
        se  *= scale;
        sec *= scale;
        #pragma unroll
        for (int p = 0; p < 4; ++p) {
            const float E = __expf(s4[p] - nm);         // exp(-inf)=0 for masked
            se += E;
            sec = fmaf(E, cv4[p], sec);
        }
        m = nm;
    }

    // ---- tail: global max first, one rescale, then add-butterflies ----
    float M = m;
    #pragma unroll
    for (int o = 1; o < 64; o <<= 1) M = fmaxf(M, __shfl_xor(M, o, 64));
    const float rs = __expf(m - M);
    se  *= rs;
    sec *= rs;
    #pragma unroll
    for (int o = 1; o < 64; o <<= 1) {
        se  += __shfl_xor(se,  o, 64);
        sec += __shfl_xor(sec, o, 64);
    }
    if (lane == 0) out[b] = sec / se;
}

extern "C" void kernel_launch(void* const* d_in, const int* in_sizes, int n_in,
                              void* d_out, int out_size, void* d_ws, size_t ws_size,
                              hipStream_t stream) {
    const float* x    = (const float*)d_in[0];
    const float* W    = (const float*)d_in[1];
    const float* bias = (const float*)d_in[2];
    const float* h    = (const float*)d_in[3];
    const float* pvec = (const float*)d_in[4];
    float* out = (float*)d_out;

    const int B = in_sizes[0] / (NFEAT * EMB);   // 8192
    attn_net_kernel<<<B / WPB, BLK, 0, stream>>>(x, W, bias, h, pvec, out);
}

// Round 14
// 37.823 us; speedup vs baseline: 2.2157x; 1.0315x over previous
//
#include <hip/hip_runtime.h>
#include <math.h>

#define NFEAT 32
#define EMB   30
#define ATT   10
#define NPAIR 496   // 32*31/2
#define BLK   64    // one wave per block (finest dispatch grain)
#define ROWSTR 36   // padded x-row stride in floats (144B; 4-bank shift per row)

typedef float v2f __attribute__((ext_vector_type(2)));

// Forced VOP3P: acc += broadcast(pr.lo or pr.hi) * w   (w in SGPR pair)
#define PK_FMA_BCLO(acc, pr, w) \
    asm("v_pk_fma_f32 %0, %1, %2, %0 op_sel:[0,0,0] op_sel_hi:[0,1,1]" \
        : "+v"(acc) : "v"(pr), "s"(w))
#define PK_FMA_BCHI(acc, pr, w) \
    asm("v_pk_fma_f32 %0, %1, %2, %0 op_sel:[1,0,0] op_sel_hi:[1,1,1]" \
        : "+v"(acc) : "v"(pr), "s"(w))
#define PK_FMA(acc, a, b) \
    asm("v_pk_fma_f32 %0, %1, %2, %0" : "+v"(acc) : "v"(a), "s"(b))
#define PK_MUL(d, a, b) \
    asm("v_pk_mul_f32 %0, %1, %2" : "=v"(d) : "v"(a), "v"(b))

// Session state: R7 (37.7us) is the champion; R8-R13 each refuted one
// mechanism (pipeline, granularity+sync, forced occupancy, hoist, setprio,
// I$ size). Invariant: VALUBusy*dur ~= 24-25us in every variant -- the FP32
// FLOP floor (~19.3us @157TF; v_pk_fma_f32 = 4cyc/wave, packed FLOPs are
// rate-bound not instruction-bound) + overhead, at a ~63% duty cap that
// occupancy does not lift. R14 = R7 inner loop VERBATIM at BLK=64/WPB=1:
// finest dispatch grain, wave code unchanged. Last untested zero-risk knob.
__global__ __launch_bounds__(BLK) __attribute__((amdgpu_waves_per_eu(3)))
void attn_net_kernel(const float* __restrict__ x,
                     const float* __restrict__ W,
                     const float* __restrict__ bias,
                     const float* __restrict__ h,
                     const float* __restrict__ pvec,
                     float* __restrict__ out)
{
    __shared__ __align__(16) float sx[NFEAT * ROWSTR];  // 4.5 KiB, one batch

    const int lane = threadIdx.x & 63;
    const int b    = blockIdx.x;

    // ---- stage x[b] into padded LDS rows (single wave: no barrier).
    //      cols 30..35 uninitialized: eg=7 consumes only e=28,29. ----
    float* swx = sx;
    {
        const float4* xin = reinterpret_cast<const float4*>(x + (size_t)b * (NFEAT * EMB));
        for (int v = lane; v < 240; v += 64) {          // exactly 240 float4s
            const float4 d = xin[v];
            const int ef = 4 * v;
            #pragma unroll
            for (int u = 0; u < 4; ++u) {
                const int e = ef + u;
                const int r = e / EMB;
                const int c = e - r * EMB;
                swx[r * ROWSTR + c] = ((const float*)&d)[u];
            }
        }
    }

    // ---- uniform params (scalar s_loads -> SGPRs) ----
    v2f b2[5], h2[5];
    #pragma unroll
    for (int a2 = 0; a2 < 5; ++a2) {
        b2[a2] = v2f{bias[2 * a2], bias[2 * a2 + 1]};
        h2[a2] = v2f{h[2 * a2],    h[2 * a2 + 1]};
    }

    // ---- per-lane: 2 chunks x one 2x2 tile (4 pairs); online softmax ----
    float m = -INFINITY, se = 0.f, sec = 0.f;

    #pragma unroll
    for (int ch = 0; ch < 2; ++ch) {
        const int T = ch * 64 + lane;
        const bool special = (T >= 120);                // only ch==1, lanes 56..63
        int r0, r1, c0, c1;
        if (special) {
            const int s7 = T - 120;
            r0 = 4 * s7; r1 = r0 + 2; c0 = r0 + 1; c1 = r0 + 3;
        } else {
            // n=16 triu inversion; exact: 961-8*T_I=(31-2I)^2, margin>=4/29
            const float sq = sqrtf((float)(961 - 8 * T));
            const int I = (int)((31.0f - sq) * 0.5f);
            const int J = I + 1 + (T - ((I * (31 - I)) >> 1));
            r0 = 2 * I; r1 = r0 + 1; c0 = 2 * J; c1 = c0 + 1;
        }
        const int oi0 = r0 * ROWSTR, oi1 = r1 * ROWSTR;
        const int oj0 = c0 * ROWSTR, oj1 = c1 * ROWSTR;

        // slots: 0:(r0,c0) 1:(r0,c1) 2:(r1,c0) 3:(r1,c1); special masks 1,2
        v2f acc[4][5];                                  // 40 VGPR
        v2f accC[4];                                    // 8 VGPR (e-pair packed)
        #pragma unroll
        for (int p = 0; p < 4; ++p) {
            #pragma unroll
            for (int a2 = 0; a2 < 5; ++a2) acc[p][a2] = b2[a2];
            accC[p] = v2f{0.f, 0.f};
        }

        #pragma unroll
        for (int eg = 0; eg < 8; ++eg) {                // e-groups of 4; eg=7 -> e=28,29
            const int e0 = eg * 4;
            const bool full = (eg < 7);
            // W rows for this e-group -> SGPR pairs (shared by all 4 pairs)
            v2f wa[5], wb[5], wc[5], wd[5];
            #pragma unroll
            for (int a2 = 0; a2 < 5; ++a2) {
                wa[a2] = v2f{W[(e0    ) * ATT + 2*a2], W[(e0    ) * ATT + 2*a2 + 1]};
                wb[a2] = v2f{W[(e0 + 1) * ATT + 2*a2], W[(e0 + 1) * ATT + 2*a2 + 1]};
            }
            if (full) {
                #pragma unroll
                for (int a2 = 0; a2 < 5; ++a2) {
                    wc[a2] = v2f{W[(e0 + 2) * ATT + 2*a2], W[(e0 + 2) * ATT + 2*a2 + 1]};
                    wd[a2] = v2f{W[(e0 + 3) * ATT + 2*a2], W[(e0 + 3) * ATT + 2*a2 + 1]};
                }
            }
            const v2f pv01 = v2f{pvec[e0], pvec[e0 + 1]};
            v2f pv23 = v2f{0.f, 0.f};
            if (full) pv23 = v2f{pvec[e0 + 2], pvec[e0 + 3]};

            const float4 xi0 = *reinterpret_cast<const float4*>(&swx[oi0 + e0]);
            const float4 xi1 = *reinterpret_cast<const float4*>(&swx[oi1 + e0]);

            auto do_pair = [&](v2f* ap, v2f& cp, const float4& xi, const float4& xj) {
                const v2f* xiv = reinterpret_cast<const v2f*>(&xi);
                const v2f* xjv = reinterpret_cast<const v2f*>(&xj);
                v2f prL;
                PK_MUL(prL, xiv[0], xjv[0]);
                #pragma unroll
                for (int a2 = 0; a2 < 5; ++a2) PK_FMA_BCLO(ap[a2], prL, wa[a2]);
                #pragma unroll
                for (int a2 = 0; a2 < 5; ++a2) PK_FMA_BCHI(ap[a2], prL, wb[a2]);
                PK_FMA(cp, prL, pv01);
                if (full) {
                    v2f prH;
                    PK_MUL(prH, xiv[1], xjv[1]);
                    #pragma unroll
                    for (int a2 = 0; a2 < 5; ++a2) PK_FMA_BCLO(ap[a2], prH, wc[a2]);
                    #pragma unroll
                    for (int a2 = 0; a2 < 5; ++a2) PK_FMA_BCHI(ap[a2], prH, wd[a2]);
                    PK_FMA(cp, prH, pv23);
                }
            };

            {   // column j0: pairs (r0,c0)->slot0, (r1,c0)->slot2
                const float4 xj = *reinterpret_cast<const float4*>(&swx[oj0 + e0]);
                do_pair(acc[0], accC[0], xi0, xj);
                do_pair(acc[2], accC[2], xi1, xj);
            }
            {   // column j1: pairs (r0,c1)->slot1, (r1,c1)->slot3
                const float4 xj = *reinterpret_cast<const float4*>(&swx[oj1 + e0]);
                do_pair(acc[1], accC[1], xi0, xj);
                do_pair(acc[3], accC[3], xi1, xj);
            }
        }

        float s4[4], cv4[4];
        #pragma unroll
        for (int p = 0; p < 4; ++p) {
            const v2f z = v2f{0.f, 0.f};
            v2f sv = z;
            #pragma unroll
            for (int a2 = 0; a2 < 5; ++a2) {
                const v2f r = __builtin_elementwise_max(acc[p][a2], z);
                sv = __builtin_elementwise_fma(r, h2[a2], sv);
            }
            s4[p]  = sv.x + sv.y;
            cv4[p] = accC[p].x + accC[p].y;
        }
        if (special) { s4[1] = -INFINITY; s4[2] = -INFINITY; }  // dup / i>j slots

        // online merge (ch=0: m=-inf -> scale=0, clean start)
        const float nm = fmaxf(m, fmaxf(fmaxf(s4[0], s4[1]), fmaxf(s4[2], s4[3])));
        const float scale = __expf(m - nm);
        se  *= scale;
        sec *= scale;
        #pragma unroll
        for (int p = 0; p < 4; ++p) {
            const float E = __expf(s4[p] - nm);         // exp(-inf)=0 for masked
            se += E;
            sec = fmaf(E, cv4[p], sec);
        }
        m = nm;
    }

    // ---- tail: global max first, one rescale, then add-butterflies ----
    float M = m;
    #pragma unroll
    for (int o = 1; o < 64; o <<= 1) M = fmaxf(M, __shfl_xor(M, o, 64));
    const float rs = __expf(m - M);
    se  *= rs;
    sec *= rs;
    #pragma unroll
    for (int o = 1; o < 64; o <<= 1) {
        se  += __shfl_xor(se,  o, 64);
        sec += __shfl_xor(sec, o, 64);
    }
    if (lane == 0) out[b] = sec / se;
}

extern "C" void kernel_launch(void* const* d_in, const int* in_sizes, int n_in,
                              void* d_out, int out_size, void* d_ws, size_t ws_size,
                              hipStream_t stream) {
    const float* x    = (const float*)d_in[0];
    const float* W    = (const float*)d_in[1];
    const float* bias = (const float*)d_in[2];
    const float* h    = (const float*)d_in[3];
    const float* pvec = (const float*)d_in[4];
    float* out = (float*)d_out;

    const int B = in_sizes[0] / (NFEAT * EMB);   // 8192
    attn_net_kernel<<<B, BLK, 0, stream>>>(x, W, bias, h, pvec, out);
}